// Round 4
// baseline (209.784 us; speedup 1.0000x reference)
//
#include <hip/hip_runtime.h>

#define NN 50000
#define NE 800000
#define DD 128

typedef __attribute__((ext_vector_type(8))) short short8v;
typedef __attribute__((ext_vector_type(4))) float float4v;

static __device__ __forceinline__ unsigned short f2b(float f) {
  union { float f; unsigned u; } v; v.f = f;
  unsigned r = v.u + 0x7fff + ((v.u >> 16) & 1);
  return (unsigned short)(r >> 16);
}
static __device__ __forceinline__ float b2f(unsigned short b) {
  union { unsigned u; float f; } v; v.u = ((unsigned)b) << 16;
  return v.f;
}

// ---------------- adjacency build: chains (coalesced) -> CSR ----------------

__global__ __launch_bounds__(256) void build_list(const int* __restrict__ src,
                                                  const int* __restrict__ dst,
                                                  int* __restrict__ head,
                                                  int* __restrict__ deg,
                                                  uint2* __restrict__ list) {
  int e = blockIdx.x * 256 + threadIdx.x;
  if (e < NE) {
    int d = dst[e];
    int old = atomicExch(&head[d], e);
    atomicAdd(&deg[d], 1);
    list[e] = make_uint2((unsigned)src[e], (unsigned)old);
  }
}

// scan1: per-block (256) exclusive scan of deg; emit block sums
__global__ __launch_bounds__(256) void scan1(const int* __restrict__ deg,
                                             int* __restrict__ exb,
                                             int* __restrict__ bsum) {
  __shared__ int ws[4];
  int i = blockIdx.x * 256 + threadIdx.x;
  int v = (i < NN) ? deg[i] : 0;
  int lane = threadIdx.x & 63, w = threadIdx.x >> 6;
  int s = v;
  #pragma unroll
  for (int off = 1; off < 64; off <<= 1) {
    int t = __shfl_up(s, off);
    if (lane >= off) s += t;
  }
  if (lane == 63) ws[w] = s;
  __syncthreads();
  int add = 0;
  for (int k = 0; k < w; ++k) add += ws[k];
  if (i < NN) exb[i] = add + s - v;
  if (threadIdx.x == 255) bsum[blockIdx.x] = add + s;
}

// scan2: single block scans the 196 block sums (exclusive)
__global__ __launch_bounds__(256) void scan2(const int* __restrict__ bsum,
                                             int* __restrict__ boff,
                                             int* __restrict__ rowptr,
                                             int nblk) {
  __shared__ int ws[4];
  int t = threadIdx.x;
  int v = (t < nblk) ? bsum[t] : 0;
  int lane = t & 63, w = t >> 6;
  int s = v;
  #pragma unroll
  for (int off = 1; off < 64; off <<= 1) {
    int u = __shfl_up(s, off);
    if (lane >= off) s += u;
  }
  if (lane == 63) ws[w] = s;
  __syncthreads();
  int add = 0;
  for (int k = 0; k < w; ++k) add += ws[k];
  if (t < nblk) boff[t] = add + s - v;
  if (t == 0) rowptr[NN] = NE;
}

// walk: one lane per node; write rowptr + node's col segment contiguously
__global__ __launch_bounds__(256) void walk_kernel(const int* __restrict__ head,
                                                   const uint2* __restrict__ list,
                                                   const int* __restrict__ exb,
                                                   const int* __restrict__ boff,
                                                   int* __restrict__ rowptr,
                                                   int* __restrict__ col) {
  int i = blockIdx.x * 256 + threadIdx.x;
  if (i >= NN) return;
  int p = exb[i] + boff[blockIdx.x];
  rowptr[i] = p;
  int e = head[i];
  while (e >= 0) {
    uint2 en = list[e];
    col[p++] = (int)en.x;
    e = (int)en.y;
  }
}

// -------- x -> bf16 convert + fp32 x.Ws dot (for residual score path) --------

__global__ __launch_bounds__(256) void conv_x(const float* __restrict__ x,
                                              const float* __restrict__ Ws,
                                              unsigned short* __restrict__ xb,
                                              float* __restrict__ xw) {
  int node = blockIdx.x * 4 + (threadIdx.x >> 6);
  if (node >= NN) return;
  int lane = threadIdx.x & 63;
  float2 v = *(const float2*)(x + (size_t)node * DD + lane * 2);
  ushort2 o; o.x = f2b(v.x); o.y = f2b(v.y);
  *(ushort2*)(xb + (size_t)node * DD + lane * 2) = o;
  float p = v.x * Ws[lane * 2] + v.y * Ws[lane * 2 + 1];
  #pragma unroll
  for (int m = 1; m < 64; m <<= 1) p += __shfl_xor(p, m);
  if (lane == 0) xw[node] = p;
}

// -------- weight prep: Wcat = [Wl | Wr] as bf16 [128][256] --------

__global__ __launch_bounds__(256) void prep_w(const float* __restrict__ Wl1,
                                              const float* __restrict__ Wr1,
                                              const float* __restrict__ Wl2,
                                              const float* __restrict__ Wr2,
                                              unsigned short* __restrict__ W1,
                                              unsigned short* __restrict__ W2) {
  int idx = blockIdx.x * 256 + threadIdx.x;  // 2 * 128 * 256 = 65536
  int half = idx >> 15;
  int i = idx & 32767;
  int o = i >> 8;
  int k = i & 255;
  const float* Wl = half ? Wl2 : Wl1;
  const float* Wr = half ? Wr2 : Wr1;
  float v = (k < DD) ? Wl[o * DD + k] : Wr[o * DD + (k - DD)];
  (half ? W2 : W1)[i] = f2b(v);
}

// ---------------- mean aggregation: CSR, 16 lanes/node, 8-deep unroll --------

__global__ __launch_bounds__(256) void agg_csr(const unsigned short* __restrict__ h,
                                               const int* __restrict__ rowptr,
                                               const int* __restrict__ col,
                                               unsigned short* __restrict__ agg) {
  int node = (blockIdx.x * 256 + threadIdx.x) >> 4;
  if (node >= NN) return;
  int q = threadIdx.x & 15;
  int beg = rowptr[node], end = rowptr[node + 1];
  float acc[8] = {0.f, 0.f, 0.f, 0.f, 0.f, 0.f, 0.f, 0.f};
  int e = beg;
  for (; e + 8 <= end; e += 8) {
    short8v v[8];
    #pragma unroll
    for (int j = 0; j < 8; ++j) {
      int s = col[e + j];
      v[j] = *(const short8v*)(h + (size_t)s * DD + q * 8);
    }
    #pragma unroll
    for (int j = 0; j < 8; ++j)
      #pragma unroll
      for (int k = 0; k < 8; ++k) acc[k] += b2f((unsigned short)v[j][k]);
  }
  for (; e < end; ++e) {
    short8v v = *(const short8v*)(h + (size_t)col[e] * DD + q * 8);
    #pragma unroll
    for (int k = 0; k < 8; ++k) acc[k] += b2f((unsigned short)v[k]);
  }
  float inv = 1.0f / fmaxf((float)(end - beg), 1.0f);
  short8v o;
  #pragma unroll
  for (int k = 0; k < 8; ++k) o[k] = (short)f2b(acc[k] * inv);
  *(short8v*)(agg + (size_t)node * DD + q * 8) = o;
}

// ---------------- fused MFMA linear layer ----------------
// Tile: 128 nodes x 128 outs, K=256 (z = [agg | h]). 4 waves, each owns 32 outs.
// W fragments kept in registers; z staged reg->LDS with XOR chunk swizzle.

template <bool SCORE>
__global__ __launch_bounds__(256) void linear_mfma(
    const unsigned short* __restrict__ aggb, const unsigned short* __restrict__ hb,
    const unsigned short* __restrict__ Wcat, const float* __restrict__ bl,
    unsigned short* __restrict__ hout,
    const float* __restrict__ Ws, const float* __restrict__ bsp,
    const float* __restrict__ alphap, const float* __restrict__ rr,
    const float* __restrict__ xw, float* __restrict__ out) {
  __shared__ unsigned short zl[128 * 256];  // 64 KiB; rows of 32 16B-chunks, chunk^=(row&7)
  __shared__ float sbuf[128];

  const int t = threadIdx.x;
  const int wid = t >> 6;
  const int l = t & 63;
  const int lg = l >> 4;   // k-group 0..3
  const int lm = l & 15;   // m (A) / n (B) within fragment
  const int node0 = blockIdx.x * 128;
  const int nb = wid * 32;

  // B fragments from global (L2-resident, 64KB reused by all blocks)
  short8v bfr[2][8];
  #pragma unroll
  for (int nf = 0; nf < 2; ++nf)
    #pragma unroll
    for (int kt = 0; kt < 8; ++kt)
      bfr[nf][kt] = *(const short8v*)(Wcat + (size_t)(nb + nf * 16 + lm) * 256 + kt * 32 + lg * 8);

  if (SCORE && t < 128) sbuf[t] = 0.f;

  // stage z = [agg | h] for 128 nodes, 16B/lane/iter, swizzled chunk placement
  #pragma unroll
  for (int q = 0; q < 16; ++q) {
    int idx = q * 256 + t;
    int row = idx >> 5;       // node-local 0..127
    int c = idx & 31;         // global k-chunk (16B = 8 bf16)
    int node = node0 + row; if (node >= NN) node = NN - 1;
    const unsigned short* src = (c < 16)
        ? (aggb + (size_t)node * DD + c * 8)
        : (hb   + (size_t)node * DD + (c - 16) * 8);
    short8v v = *(const short8v*)src;
    int cs = c ^ (row & 7);
    *(short8v*)(&zl[row * 256 + cs * 8]) = v;
  }
  __syncthreads();

  float4v acc[8][2];
  #pragma unroll
  for (int mf = 0; mf < 8; ++mf) {
    acc[mf][0] = (float4v){0.f, 0.f, 0.f, 0.f};
    acc[mf][1] = (float4v){0.f, 0.f, 0.f, 0.f};
  }

  #pragma unroll
  for (int kt = 0; kt < 8; ++kt) {
    short8v afr[8];
    #pragma unroll
    for (int mf = 0; mf < 8; ++mf) {
      int row = mf * 16 + lm;
      int c = (kt * 4 + lg) ^ (row & 7);
      afr[mf] = *(const short8v*)(&zl[row * 256 + c * 8]);
    }
    #pragma unroll
    for (int mf = 0; mf < 8; ++mf) {
      acc[mf][0] = __builtin_amdgcn_mfma_f32_16x16x32_bf16(afr[mf], bfr[0][kt], acc[mf][0], 0, 0, 0);
      acc[mf][1] = __builtin_amdgcn_mfma_f32_16x16x32_bf16(afr[mf], bfr[1][kt], acc[mf][1], 0, 0, 0);
    }
  }

  const float b0 = bl[nb + lm];
  const float b1 = bl[nb + 16 + lm];

  if (!SCORE) {
    #pragma unroll
    for (int mf = 0; mf < 8; ++mf) {
      #pragma unroll
      for (int r = 0; r < 4; ++r) {
        int row = node0 + mf * 16 + lg * 4 + r;
        if (row < NN) {
          hout[(size_t)row * DD + nb + lm]      = f2b(fmaxf(acc[mf][0][r] + b0, 0.f));
          hout[(size_t)row * DD + nb + 16 + lm] = f2b(fmaxf(acc[mf][1][r] + b1, 0.f));
        }
      }
    }
  } else {
    const float w0 = Ws[nb + lm];
    const float w1 = Ws[nb + 16 + lm];
    #pragma unroll
    for (int mf = 0; mf < 8; ++mf) {
      #pragma unroll
      for (int r = 0; r < 4; ++r) {
        float p = fmaxf(acc[mf][0][r] + b0, 0.f) * w0
                + fmaxf(acc[mf][1][r] + b1, 0.f) * w1;
        p += __shfl_xor(p, 1);
        p += __shfl_xor(p, 2);
        p += __shfl_xor(p, 4);
        p += __shfl_xor(p, 8);
        if (lm == 0) atomicAdd(&sbuf[mf * 16 + lg * 4 + r], p);
      }
    }
    __syncthreads();
    if (t < 128) {
      int node = node0 + t;
      if (node < NN) {
        float a = 1.f / (1.f + expf(-alphap[0]));
        float score = sbuf[t] + xw[node] + bsp[0];
        out[node] = a * rr[node] + (1.f - a) * score;
      }
    }
  }
}

// ---------------- launch ----------------

extern "C" void kernel_launch(void* const* d_in, const int* in_sizes, int n_in,
                              void* d_out, int out_size, void* d_ws, size_t ws_size,
                              hipStream_t stream) {
  const float* x   = (const float*)d_in[0];
  const int*   ei  = (const int*)d_in[1];
  const float* rr  = (const float*)d_in[2];
  const float* Wl1 = (const float*)d_in[3];
  const float* bl1 = (const float*)d_in[4];
  const float* Wr1 = (const float*)d_in[5];
  const float* Wl2 = (const float*)d_in[6];
  const float* bl2 = (const float*)d_in[7];
  const float* Wr2 = (const float*)d_in[8];
  const float* Wsc = (const float*)d_in[9];
  const float* bs  = (const float*)d_in[10];
  const float* al  = (const float*)d_in[11];
  const int* srcv = ei;
  const int* dstv = ei + NE;
  float* out = (float*)d_out;

  const int NBLK = (NN + 255) / 256;  // 196

  size_t off = 0;
  auto nxt = [&](size_t bytes) {
    size_t cur = off; off += (bytes + 255) & ~(size_t)255; return cur;
  };
  int*            head   = (int*)((char*)d_ws + nxt((size_t)NN * 4));
  int*            deg    = (int*)((char*)d_ws + nxt((size_t)NN * 4));
  int*            exb    = (int*)((char*)d_ws + nxt((size_t)NN * 4));
  int*            bsum   = (int*)((char*)d_ws + nxt((size_t)NBLK * 4));
  int*            boff   = (int*)((char*)d_ws + nxt((size_t)NBLK * 4));
  int*            rowptr = (int*)((char*)d_ws + nxt((size_t)(NN + 1) * 4));
  int*            col    = (int*)((char*)d_ws + nxt((size_t)NE * 4));
  uint2*          list   = (uint2*)((char*)d_ws + nxt((size_t)NE * 8));
  unsigned short* xb     = (unsigned short*)((char*)d_ws + nxt((size_t)NN * DD * 2));
  unsigned short* aggb   = (unsigned short*)((char*)d_ws + nxt((size_t)NN * DD * 2));
  unsigned short* h1b    = (unsigned short*)((char*)d_ws + nxt((size_t)NN * DD * 2));
  unsigned short* W1     = (unsigned short*)((char*)d_ws + nxt((size_t)DD * 256 * 2));
  unsigned short* W2     = (unsigned short*)((char*)d_ws + nxt((size_t)DD * 256 * 2));
  float*          xw     = (float*)((char*)d_ws + nxt((size_t)NN * 4));

  hipMemsetAsync(head, 0xFF, (size_t)NN * 4, stream);  // head = -1
  hipMemsetAsync(deg, 0, (size_t)NN * 4, stream);
  build_list<<<(NE + 255) / 256, 256, 0, stream>>>(srcv, dstv, head, deg, list);
  scan1<<<NBLK, 256, 0, stream>>>(deg, exb, bsum);
  scan2<<<1, 256, 0, stream>>>(bsum, boff, rowptr, NBLK);
  walk_kernel<<<NBLK, 256, 0, stream>>>(head, list, exb, boff, rowptr, col);

  conv_x<<<(NN + 3) / 4, 256, 0, stream>>>(x, Wsc, xb, xw);
  prep_w<<<256, 256, 0, stream>>>(Wl1, Wr1, Wl2, Wr2, W1, W2);

  // layer 1
  agg_csr<<<(NN * 16 + 255) / 256, 256, 0, stream>>>(xb, rowptr, col, aggb);
  linear_mfma<false><<<(NN + 127) / 128, 256, 0, stream>>>(
      aggb, xb, W1, bl1, h1b, nullptr, nullptr, nullptr, nullptr, nullptr, nullptr);
  // layer 2 (+ residual + score head + blend, fused)
  agg_csr<<<(NN * 16 + 255) / 256, 256, 0, stream>>>(h1b, rowptr, col, aggb);
  linear_mfma<true><<<(NN + 127) / 128, 256, 0, stream>>>(
      aggb, h1b, W2, bl2, nullptr, Wsc, bs, al, rr, xw, out);
}

// Round 5
// 189.607 us; speedup vs baseline: 1.1064x; 1.1064x over previous
//
#include <hip/hip_runtime.h>

#define NN 50000
#define NE 800000
#define DD 128

#define NBUCK 196   // ceil(NN/256), bucket = dst >> 8
#define EPB   2048  // edges per block in pass 1
#define B1    391   // ceil(NE/EPB)
#define CAP   5120  // max edges per bucket (mean 4082, std 64 -> +16 sigma)

typedef __attribute__((ext_vector_type(8))) short short8v;
typedef __attribute__((ext_vector_type(4))) float float4v;

static __device__ __forceinline__ unsigned short f2b(float f) {
  union { float f; unsigned u; } v; v.f = f;
  unsigned r = v.u + 0x7fff + ((v.u >> 16) & 1);
  return (unsigned short)(r >> 16);
}
static __device__ __forceinline__ float b2f(unsigned short b) {
  union { unsigned u; float f; } v; v.u = ((unsigned)b) << 16;
  return v.f;
}

// ---------------- CSR build via two-level bucket sort (no global atomics) ----

__global__ __launch_bounds__(256) void hist1(const int* __restrict__ dst,
                                             int* __restrict__ ghist) {
  __shared__ int hs[NBUCK];
  for (int i = threadIdx.x; i < NBUCK; i += 256) hs[i] = 0;
  __syncthreads();
  int base = blockIdx.x * EPB;
  for (int i = threadIdx.x; i < EPB; i += 256) {
    int e = base + i;
    if (e < NE) atomicAdd(&hs[dst[e] >> 8], 1);
  }
  __syncthreads();
  for (int i = threadIdx.x; i < NBUCK; i += 256)
    ghist[blockIdx.x * NBUCK + i] = hs[i];
}

// one block: bucket starts + per-(block,bucket) base offsets
__global__ __launch_bounds__(256) void scanbuckets(const int* __restrict__ ghist,
                                                   int* __restrict__ goff,
                                                   int* __restrict__ binstart) {
  __shared__ int ws[4];
  const int j = threadIdx.x;
  int t = 0;
  if (j < NBUCK) {
    #pragma unroll 4
    for (int b = 0; b < B1; ++b) t += ghist[b * NBUCK + j];
  }
  // exclusive scan of per-bucket totals over 256 threads
  int lane = j & 63, w = j >> 6;
  int s = t;
  #pragma unroll
  for (int off = 1; off < 64; off <<= 1) {
    int u = __shfl_up(s, off);
    if (lane >= off) s += u;
  }
  if (lane == 63) ws[w] = s;
  __syncthreads();
  int add = 0;
  for (int k = 0; k < w; ++k) add += ws[k];
  int excl = add + s - t;
  if (j < NBUCK) binstart[j] = excl;
  if (j == 0) binstart[NBUCK] = NE;
  if (j < NBUCK) {
    int run = excl;
    #pragma unroll 4
    for (int b = 0; b < B1; ++b) {
      int c = ghist[b * NBUCK + j];
      goff[b * NBUCK + j] = run;
      run += c;
    }
  }
}

__global__ __launch_bounds__(256) void scatter1(const int* __restrict__ src,
                                                const int* __restrict__ dst,
                                                const int* __restrict__ goff,
                                                unsigned* __restrict__ tmp) {
  __shared__ int cur[NBUCK];
  for (int i = threadIdx.x; i < NBUCK; i += 256)
    cur[i] = goff[blockIdx.x * NBUCK + i];
  __syncthreads();
  int base = blockIdx.x * EPB;
  for (int i = threadIdx.x; i < EPB; i += 256) {
    int e = base + i;
    if (e < NE) {
      int d = dst[e];
      int pos = atomicAdd(&cur[d >> 8], 1);
      tmp[pos] = ((unsigned)(d & 255) << 20) | (unsigned)src[e];
    }
  }
}

// one block per bucket: LDS counting sort on low 8 bits -> rowptr + col
__global__ __launch_bounds__(256) void bucketsort(const unsigned* __restrict__ tmp,
                                                  const int* __restrict__ binstart,
                                                  int* __restrict__ rowptr,
                                                  int* __restrict__ col) {
  __shared__ unsigned vals[CAP];
  __shared__ int cnt[256];
  __shared__ int ws[4];
  const int b = blockIdx.x;
  const int j = threadIdx.x;
  const int s0 = binstart[b];
  int n = binstart[b + 1] - s0;
  if (n > CAP) n = CAP;
  cnt[j] = 0;
  __syncthreads();
  for (int i = j; i < n; i += 256) {
    unsigned v = tmp[s0 + i];
    vals[i] = v;
    atomicAdd(&cnt[v >> 20], 1);
  }
  __syncthreads();
  int c = cnt[j];
  int lane = j & 63, w = j >> 6;
  int s = c;
  #pragma unroll
  for (int off = 1; off < 64; off <<= 1) {
    int u = __shfl_up(s, off);
    if (lane >= off) s += u;
  }
  if (lane == 63) ws[w] = s;
  __syncthreads();
  int add = 0;
  for (int k = 0; k < w; ++k) add += ws[k];
  int excl = add + s - c;
  int node = b * 256 + j;
  if (node < NN) rowptr[node] = s0 + excl;
  if (b == 0 && j == 0) rowptr[NN] = NE;
  cnt[j] = excl;  // reuse as cursor (all reads of cnt done before ws barrier)
  __syncthreads();
  for (int i = j; i < n; i += 256) {
    unsigned v = vals[i];
    int pos = atomicAdd(&cnt[v >> 20], 1);
    col[s0 + pos] = (int)(v & 0xFFFFF);
  }
}

// -------- x -> bf16 convert + fp32 x.Ws dot (for residual score path) --------

__global__ __launch_bounds__(256) void conv_x(const float* __restrict__ x,
                                              const float* __restrict__ Ws,
                                              unsigned short* __restrict__ xb,
                                              float* __restrict__ xw) {
  int node = blockIdx.x * 4 + (threadIdx.x >> 6);
  if (node >= NN) return;
  int lane = threadIdx.x & 63;
  float2 v = *(const float2*)(x + (size_t)node * DD + lane * 2);
  ushort2 o; o.x = f2b(v.x); o.y = f2b(v.y);
  *(ushort2*)(xb + (size_t)node * DD + lane * 2) = o;
  float p = v.x * Ws[lane * 2] + v.y * Ws[lane * 2 + 1];
  #pragma unroll
  for (int m = 1; m < 64; m <<= 1) p += __shfl_xor(p, m);
  if (lane == 0) xw[node] = p;
}

// -------- weight prep: Wcat = [Wl | Wr] as bf16 [128][256] --------

__global__ __launch_bounds__(256) void prep_w(const float* __restrict__ Wl1,
                                              const float* __restrict__ Wr1,
                                              const float* __restrict__ Wl2,
                                              const float* __restrict__ Wr2,
                                              unsigned short* __restrict__ W1,
                                              unsigned short* __restrict__ W2) {
  int idx = blockIdx.x * 256 + threadIdx.x;  // 2 * 128 * 256 = 65536
  int half = idx >> 15;
  int i = idx & 32767;
  int o = i >> 8;
  int k = i & 255;
  const float* Wl = half ? Wl2 : Wl1;
  const float* Wr = half ? Wr2 : Wr1;
  float v = (k < DD) ? Wl[o * DD + k] : Wr[o * DD + (k - DD)];
  (half ? W2 : W1)[i] = f2b(v);
}

// ---------------- mean aggregation: CSR, 16 lanes/node, 8-deep unroll --------

__global__ __launch_bounds__(256) void agg_csr(const unsigned short* __restrict__ h,
                                               const int* __restrict__ rowptr,
                                               const int* __restrict__ col,
                                               unsigned short* __restrict__ agg) {
  int node = (blockIdx.x * 256 + threadIdx.x) >> 4;
  if (node >= NN) return;
  int q = threadIdx.x & 15;
  int beg = rowptr[node], end = rowptr[node + 1];
  float acc[8] = {0.f, 0.f, 0.f, 0.f, 0.f, 0.f, 0.f, 0.f};
  int e = beg;
  for (; e + 8 <= end; e += 8) {
    short8v v[8];
    #pragma unroll
    for (int j = 0; j < 8; ++j) {
      int s = col[e + j];
      v[j] = *(const short8v*)(h + (size_t)s * DD + q * 8);
    }
    #pragma unroll
    for (int j = 0; j < 8; ++j)
      #pragma unroll
      for (int k = 0; k < 8; ++k) acc[k] += b2f((unsigned short)v[j][k]);
  }
  for (; e < end; ++e) {
    short8v v = *(const short8v*)(h + (size_t)col[e] * DD + q * 8);
    #pragma unroll
    for (int k = 0; k < 8; ++k) acc[k] += b2f((unsigned short)v[k]);
  }
  float inv = 1.0f / fmaxf((float)(end - beg), 1.0f);
  short8v o;
  #pragma unroll
  for (int k = 0; k < 8; ++k) o[k] = (short)f2b(acc[k] * inv);
  *(short8v*)(agg + (size_t)node * DD + q * 8) = o;
}

// ---------------- fused MFMA linear layer ----------------
// Tile: 128 nodes x 128 outs, K=256 (z = [agg | h]). 4 waves, each owns 32 outs.
// W fragments kept in registers; z staged reg->LDS with XOR chunk swizzle.

template <bool SCORE>
__global__ __launch_bounds__(256) void linear_mfma(
    const unsigned short* __restrict__ aggb, const unsigned short* __restrict__ hb,
    const unsigned short* __restrict__ Wcat, const float* __restrict__ bl,
    unsigned short* __restrict__ hout,
    const float* __restrict__ Ws, const float* __restrict__ bsp,
    const float* __restrict__ alphap, const float* __restrict__ rr,
    const float* __restrict__ xw, float* __restrict__ out) {
  __shared__ unsigned short zl[128 * 256];  // 64 KiB; rows of 32 16B-chunks, chunk^=(row&7)
  __shared__ float sbuf[128];

  const int t = threadIdx.x;
  const int wid = t >> 6;
  const int l = t & 63;
  const int lg = l >> 4;   // k-group 0..3
  const int lm = l & 15;   // m (A) / n (B) within fragment
  const int node0 = blockIdx.x * 128;
  const int nb = wid * 32;

  // B fragments from global (L2-resident, 64KB reused by all blocks)
  short8v bfr[2][8];
  #pragma unroll
  for (int nf = 0; nf < 2; ++nf)
    #pragma unroll
    for (int kt = 0; kt < 8; ++kt)
      bfr[nf][kt] = *(const short8v*)(Wcat + (size_t)(nb + nf * 16 + lm) * 256 + kt * 32 + lg * 8);

  if (SCORE && t < 128) sbuf[t] = 0.f;

  // stage z = [agg | h] for 128 nodes, 16B/lane/iter, swizzled chunk placement
  #pragma unroll
  for (int q = 0; q < 16; ++q) {
    int idx = q * 256 + t;
    int row = idx >> 5;       // node-local 0..127
    int c = idx & 31;         // global k-chunk (16B = 8 bf16)
    int node = node0 + row; if (node >= NN) node = NN - 1;
    const unsigned short* src = (c < 16)
        ? (aggb + (size_t)node * DD + c * 8)
        : (hb   + (size_t)node * DD + (c - 16) * 8);
    short8v v = *(const short8v*)src;
    int cs = c ^ (row & 7);
    *(short8v*)(&zl[row * 256 + cs * 8]) = v;
  }
  __syncthreads();

  float4v acc[8][2];
  #pragma unroll
  for (int mf = 0; mf < 8; ++mf) {
    acc[mf][0] = (float4v){0.f, 0.f, 0.f, 0.f};
    acc[mf][1] = (float4v){0.f, 0.f, 0.f, 0.f};
  }

  #pragma unroll
  for (int kt = 0; kt < 8; ++kt) {
    short8v afr[8];
    #pragma unroll
    for (int mf = 0; mf < 8; ++mf) {
      int row = mf * 16 + lm;
      int c = (kt * 4 + lg) ^ (row & 7);
      afr[mf] = *(const short8v*)(&zl[row * 256 + c * 8]);
    }
    #pragma unroll
    for (int mf = 0; mf < 8; ++mf) {
      acc[mf][0] = __builtin_amdgcn_mfma_f32_16x16x32_bf16(afr[mf], bfr[0][kt], acc[mf][0], 0, 0, 0);
      acc[mf][1] = __builtin_amdgcn_mfma_f32_16x16x32_bf16(afr[mf], bfr[1][kt], acc[mf][1], 0, 0, 0);
    }
  }

  const float b0 = bl[nb + lm];
  const float b1 = bl[nb + 16 + lm];

  if (!SCORE) {
    #pragma unroll
    for (int mf = 0; mf < 8; ++mf) {
      #pragma unroll
      for (int r = 0; r < 4; ++r) {
        int row = node0 + mf * 16 + lg * 4 + r;
        if (row < NN) {
          hout[(size_t)row * DD + nb + lm]      = f2b(fmaxf(acc[mf][0][r] + b0, 0.f));
          hout[(size_t)row * DD + nb + 16 + lm] = f2b(fmaxf(acc[mf][1][r] + b1, 0.f));
        }
      }
    }
  } else {
    const float w0 = Ws[nb + lm];
    const float w1 = Ws[nb + 16 + lm];
    #pragma unroll
    for (int mf = 0; mf < 8; ++mf) {
      #pragma unroll
      for (int r = 0; r < 4; ++r) {
        float p = fmaxf(acc[mf][0][r] + b0, 0.f) * w0
                + fmaxf(acc[mf][1][r] + b1, 0.f) * w1;
        p += __shfl_xor(p, 1);
        p += __shfl_xor(p, 2);
        p += __shfl_xor(p, 4);
        p += __shfl_xor(p, 8);
        if (lm == 0) atomicAdd(&sbuf[mf * 16 + lg * 4 + r], p);
      }
    }
    __syncthreads();
    if (t < 128) {
      int node = node0 + t;
      if (node < NN) {
        float a = 1.f / (1.f + expf(-alphap[0]));
        float score = sbuf[t] + xw[node] + bsp[0];
        out[node] = a * rr[node] + (1.f - a) * score;
      }
    }
  }
}

// ---------------- launch ----------------

extern "C" void kernel_launch(void* const* d_in, const int* in_sizes, int n_in,
                              void* d_out, int out_size, void* d_ws, size_t ws_size,
                              hipStream_t stream) {
  const float* x   = (const float*)d_in[0];
  const int*   ei  = (const int*)d_in[1];
  const float* rr  = (const float*)d_in[2];
  const float* Wl1 = (const float*)d_in[3];
  const float* bl1 = (const float*)d_in[4];
  const float* Wr1 = (const float*)d_in[5];
  const float* Wl2 = (const float*)d_in[6];
  const float* bl2 = (const float*)d_in[7];
  const float* Wr2 = (const float*)d_in[8];
  const float* Wsc = (const float*)d_in[9];
  const float* bs  = (const float*)d_in[10];
  const float* al  = (const float*)d_in[11];
  const int* srcv = ei;
  const int* dstv = ei + NE;
  float* out = (float*)d_out;

  size_t off = 0;
  auto nxt = [&](size_t bytes) {
    size_t cur = off; off += (bytes + 255) & ~(size_t)255; return cur;
  };
  int*            ghist    = (int*)((char*)d_ws + nxt((size_t)B1 * NBUCK * 4));
  int*            goff     = (int*)((char*)d_ws + nxt((size_t)B1 * NBUCK * 4));
  int*            binstart = (int*)((char*)d_ws + nxt((size_t)(NBUCK + 1) * 4));
  int*            rowptr   = (int*)((char*)d_ws + nxt((size_t)(NN + 1) * 4));
  int*            col      = (int*)((char*)d_ws + nxt((size_t)NE * 4));
  unsigned*       tmp      = (unsigned*)((char*)d_ws + nxt((size_t)NE * 4));
  unsigned short* xb       = (unsigned short*)((char*)d_ws + nxt((size_t)NN * DD * 2));
  unsigned short* aggb     = (unsigned short*)((char*)d_ws + nxt((size_t)NN * DD * 2));
  unsigned short* h1b      = (unsigned short*)((char*)d_ws + nxt((size_t)NN * DD * 2));
  unsigned short* W1       = (unsigned short*)((char*)d_ws + nxt((size_t)DD * 256 * 2));
  unsigned short* W2       = (unsigned short*)((char*)d_ws + nxt((size_t)DD * 256 * 2));
  float*          xw       = (float*)((char*)d_ws + nxt((size_t)NN * 4));

  hist1<<<B1, 256, 0, stream>>>(dstv, ghist);
  scanbuckets<<<1, 256, 0, stream>>>(ghist, goff, binstart);
  scatter1<<<B1, 256, 0, stream>>>(srcv, dstv, goff, tmp);
  bucketsort<<<NBUCK, 256, 0, stream>>>(tmp, binstart, rowptr, col);

  conv_x<<<(NN + 3) / 4, 256, 0, stream>>>(x, Wsc, xb, xw);
  prep_w<<<256, 256, 0, stream>>>(Wl1, Wr1, Wl2, Wr2, W1, W2);

  // layer 1
  agg_csr<<<(NN * 16 + 255) / 256, 256, 0, stream>>>(xb, rowptr, col, aggb);
  linear_mfma<false><<<(NN + 127) / 128, 256, 0, stream>>>(
      aggb, xb, W1, bl1, h1b, nullptr, nullptr, nullptr, nullptr, nullptr, nullptr);
  // layer 2 (+ residual + score head + blend, fused)
  agg_csr<<<(NN * 16 + 255) / 256, 256, 0, stream>>>(h1b, rowptr, col, aggb);
  linear_mfma<true><<<(NN + 127) / 128, 256, 0, stream>>>(
      aggb, h1b, W2, bl2, nullptr, Wsc, bs, al, rr, xw, out);
}

// Round 6
// 139.120 us; speedup vs baseline: 1.5079x; 1.3629x over previous
//
#include <hip/hip_runtime.h>

#define NN 50000
#define NE 800000
#define DD 128

#define NBUCK 196   // ceil(NN/256), bucket = dst >> 8
#define EPB   2048  // edges per block in pass 1
#define B1    391   // ceil(NE/EPB)
#define CAP   5120  // max edges per bucket (mean 4082, std 64 -> +16 sigma)

typedef __attribute__((ext_vector_type(8))) short short8v;
typedef __attribute__((ext_vector_type(4))) float float4v;

static __device__ __forceinline__ unsigned short f2b(float f) {
  union { float f; unsigned u; } v; v.f = f;
  unsigned r = v.u + 0x7fff + ((v.u >> 16) & 1);
  return (unsigned short)(r >> 16);
}
static __device__ __forceinline__ float b2f(unsigned short b) {
  union { unsigned u; float f; } v; v.u = ((unsigned)b) << 16;
  return v.f;
}

// ---------------- CSR build via two-level bucket sort (no global atomics) ----

__global__ __launch_bounds__(256) void hist1(const int* __restrict__ dst,
                                             int* __restrict__ ghist) {
  __shared__ int hs[NBUCK];
  for (int i = threadIdx.x; i < NBUCK; i += 256) hs[i] = 0;
  __syncthreads();
  int base = blockIdx.x * EPB;
  for (int i = threadIdx.x; i < EPB; i += 256) {
    int e = base + i;
    if (e < NE) atomicAdd(&hs[dst[e] >> 8], 1);
  }
  __syncthreads();
  for (int i = threadIdx.x; i < NBUCK; i += 256)
    ghist[blockIdx.x * NBUCK + i] = hs[i];
}

// one block PER BUCKET: scan that bucket's 391 per-block counts
__global__ __launch_bounds__(256) void scan_cols(const int* __restrict__ ghist,
                                                 int* __restrict__ goff,
                                                 int* __restrict__ btot) {
  __shared__ int ws[4];
  const int j = blockIdx.x;
  const int t = threadIdx.x;
  int b0 = 2 * t, b1 = 2 * t + 1;
  int v0 = (b0 < B1) ? ghist[b0 * NBUCK + j] : 0;
  int v1 = (b1 < B1) ? ghist[b1 * NBUCK + j] : 0;
  int tsum = v0 + v1;
  int lane = t & 63, w = t >> 6;
  int s = tsum;
  #pragma unroll
  for (int off = 1; off < 64; off <<= 1) {
    int u = __shfl_up(s, off);
    if (lane >= off) s += u;
  }
  if (lane == 63) ws[w] = s;
  __syncthreads();
  int add = 0;
  for (int k = 0; k < w; ++k) add += ws[k];
  int excl = add + s - tsum;
  if (b0 < B1) goff[b0 * NBUCK + j] = excl;
  if (b1 < B1) goff[b1 * NBUCK + j] = excl + v0;
  if (t == 255) btot[j] = add + s;
}

// one tiny block: exclusive scan of 196 bucket totals -> binstart
__global__ __launch_bounds__(256) void scan_btot(const int* __restrict__ btot,
                                                 int* __restrict__ binstart) {
  __shared__ int ws[4];
  const int t = threadIdx.x;
  int v = (t < NBUCK) ? btot[t] : 0;
  int lane = t & 63, w = t >> 6;
  int s = v;
  #pragma unroll
  for (int off = 1; off < 64; off <<= 1) {
    int u = __shfl_up(s, off);
    if (lane >= off) s += u;
  }
  if (lane == 63) ws[w] = s;
  __syncthreads();
  int add = 0;
  for (int k = 0; k < w; ++k) add += ws[k];
  if (t < NBUCK) binstart[t] = add + s - v;
  if (t == 0) binstart[NBUCK] = NE;
}

__global__ __launch_bounds__(256) void scatter1(const int* __restrict__ src,
                                                const int* __restrict__ dst,
                                                const int* __restrict__ goff,
                                                const int* __restrict__ binstart,
                                                unsigned* __restrict__ tmp) {
  __shared__ int cur[NBUCK];
  for (int i = threadIdx.x; i < NBUCK; i += 256)
    cur[i] = binstart[i] + goff[blockIdx.x * NBUCK + i];
  __syncthreads();
  int base = blockIdx.x * EPB;
  for (int i = threadIdx.x; i < EPB; i += 256) {
    int e = base + i;
    if (e < NE) {
      int d = dst[e];
      int pos = atomicAdd(&cur[d >> 8], 1);
      tmp[pos] = ((unsigned)(d & 255) << 20) | (unsigned)src[e];
    }
  }
}

// one block per bucket: LDS counting sort on low 8 bits -> rowptr + col
__global__ __launch_bounds__(256) void bucketsort(const unsigned* __restrict__ tmp,
                                                  const int* __restrict__ binstart,
                                                  int* __restrict__ rowptr,
                                                  int* __restrict__ col) {
  __shared__ unsigned vals[CAP];
  __shared__ int cnt[256];
  __shared__ int ws[4];
  const int b = blockIdx.x;
  const int j = threadIdx.x;
  const int s0 = binstart[b];
  int n = binstart[b + 1] - s0;
  if (n > CAP) n = CAP;
  cnt[j] = 0;
  __syncthreads();
  for (int i = j; i < n; i += 256) {
    unsigned v = tmp[s0 + i];
    vals[i] = v;
    atomicAdd(&cnt[v >> 20], 1);
  }
  __syncthreads();
  int c = cnt[j];
  int lane = j & 63, w = j >> 6;
  int s = c;
  #pragma unroll
  for (int off = 1; off < 64; off <<= 1) {
    int u = __shfl_up(s, off);
    if (lane >= off) s += u;
  }
  if (lane == 63) ws[w] = s;
  __syncthreads();
  int add = 0;
  for (int k = 0; k < w; ++k) add += ws[k];
  int excl = add + s - c;
  int node = b * 256 + j;
  if (node < NN) rowptr[node] = s0 + excl;
  if (b == 0 && j == 0) rowptr[NN] = NE;
  cnt[j] = excl;  // reuse as cursor
  __syncthreads();
  for (int i = j; i < n; i += 256) {
    unsigned v = vals[i];
    int pos = atomicAdd(&cnt[v >> 20], 1);
    col[s0 + pos] = (int)(v & 0xFFFFF);
  }
}

// -------- x -> bf16 convert + fp32 x.Ws dot (for residual score path) --------

__global__ __launch_bounds__(256) void conv_x(const float* __restrict__ x,
                                              const float* __restrict__ Ws,
                                              unsigned short* __restrict__ xb,
                                              float* __restrict__ xw) {
  int node = blockIdx.x * 4 + (threadIdx.x >> 6);
  if (node >= NN) return;
  int lane = threadIdx.x & 63;
  float2 v = *(const float2*)(x + (size_t)node * DD + lane * 2);
  ushort2 o; o.x = f2b(v.x); o.y = f2b(v.y);
  *(ushort2*)(xb + (size_t)node * DD + lane * 2) = o;
  float p = v.x * Ws[lane * 2] + v.y * Ws[lane * 2 + 1];
  #pragma unroll
  for (int m = 1; m < 64; m <<= 1) p += __shfl_xor(p, m);
  if (lane == 0) xw[node] = p;
}

// -------- weight prep: Wcat = [Wl | Wr] as bf16 [128][256] --------

__global__ __launch_bounds__(256) void prep_w(const float* __restrict__ Wl1,
                                              const float* __restrict__ Wr1,
                                              const float* __restrict__ Wl2,
                                              const float* __restrict__ Wr2,
                                              unsigned short* __restrict__ W1,
                                              unsigned short* __restrict__ W2) {
  int idx = blockIdx.x * 256 + threadIdx.x;  // 2 * 128 * 256 = 65536
  int half = idx >> 15;
  int i = idx & 32767;
  int o = i >> 8;
  int k = i & 255;
  const float* Wl = half ? Wl2 : Wl1;
  const float* Wr = half ? Wr2 : Wr1;
  float v = (k < DD) ? Wl[o * DD + k] : Wr[o * DD + (k - DD)];
  (half ? W2 : W1)[i] = f2b(v);
}

// ---------------- mean aggregation: CSR, 16 lanes/node, 8-deep unroll --------

__global__ __launch_bounds__(256) void agg_csr(const unsigned short* __restrict__ h,
                                               const int* __restrict__ rowptr,
                                               const int* __restrict__ col,
                                               unsigned short* __restrict__ agg) {
  int node = (blockIdx.x * 256 + threadIdx.x) >> 4;
  if (node >= NN) return;
  int q = threadIdx.x & 15;
  int beg = rowptr[node], end = rowptr[node + 1];
  float acc[8] = {0.f, 0.f, 0.f, 0.f, 0.f, 0.f, 0.f, 0.f};
  int e = beg;
  for (; e + 8 <= end; e += 8) {
    short8v v[8];
    #pragma unroll
    for (int j = 0; j < 8; ++j) {
      int s = col[e + j];
      v[j] = *(const short8v*)(h + (size_t)s * DD + q * 8);
    }
    #pragma unroll
    for (int j = 0; j < 8; ++j)
      #pragma unroll
      for (int k = 0; k < 8; ++k) acc[k] += b2f((unsigned short)v[j][k]);
  }
  for (; e < end; ++e) {
    short8v v = *(const short8v*)(h + (size_t)col[e] * DD + q * 8);
    #pragma unroll
    for (int k = 0; k < 8; ++k) acc[k] += b2f((unsigned short)v[k]);
  }
  float inv = 1.0f / fmaxf((float)(end - beg), 1.0f);
  short8v o;
  #pragma unroll
  for (int k = 0; k < 8; ++k) o[k] = (short)f2b(acc[k] * inv);
  *(short8v*)(agg + (size_t)node * DD + q * 8) = o;
}

// ---------------- fused MFMA linear layer ----------------
// Tile: 128 nodes x 128 outs, K=256 (z = [agg | h]). 4 waves, each owns 32 outs.
// W fragments kept in registers; z staged reg->LDS with XOR chunk swizzle.

template <bool SCORE>
__global__ __launch_bounds__(256) void linear_mfma(
    const unsigned short* __restrict__ aggb, const unsigned short* __restrict__ hb,
    const unsigned short* __restrict__ Wcat, const float* __restrict__ bl,
    unsigned short* __restrict__ hout,
    const float* __restrict__ Ws, const float* __restrict__ bsp,
    const float* __restrict__ alphap, const float* __restrict__ rr,
    const float* __restrict__ xw, float* __restrict__ out) {
  __shared__ unsigned short zl[128 * 256];  // 64 KiB; rows of 32 16B-chunks, chunk^=(row&7)
  __shared__ float sbuf[128];

  const int t = threadIdx.x;
  const int wid = t >> 6;
  const int l = t & 63;
  const int lg = l >> 4;   // k-group 0..3
  const int lm = l & 15;   // m (A) / n (B) within fragment
  const int node0 = blockIdx.x * 128;
  const int nb = wid * 32;

  // B fragments from global (L2-resident, 64KB reused by all blocks)
  short8v bfr[2][8];
  #pragma unroll
  for (int nf = 0; nf < 2; ++nf)
    #pragma unroll
    for (int kt = 0; kt < 8; ++kt)
      bfr[nf][kt] = *(const short8v*)(Wcat + (size_t)(nb + nf * 16 + lm) * 256 + kt * 32 + lg * 8);

  if (SCORE && t < 128) sbuf[t] = 0.f;

  // stage z = [agg | h] for 128 nodes, 16B/lane/iter, swizzled chunk placement
  #pragma unroll
  for (int q = 0; q < 16; ++q) {
    int idx = q * 256 + t;
    int row = idx >> 5;       // node-local 0..127
    int c = idx & 31;         // global k-chunk (16B = 8 bf16)
    int node = node0 + row; if (node >= NN) node = NN - 1;
    const unsigned short* src = (c < 16)
        ? (aggb + (size_t)node * DD + c * 8)
        : (hb   + (size_t)node * DD + (c - 16) * 8);
    short8v v = *(const short8v*)src;
    int cs = c ^ (row & 7);
    *(short8v*)(&zl[row * 256 + cs * 8]) = v;
  }
  __syncthreads();

  float4v acc[8][2];
  #pragma unroll
  for (int mf = 0; mf < 8; ++mf) {
    acc[mf][0] = (float4v){0.f, 0.f, 0.f, 0.f};
    acc[mf][1] = (float4v){0.f, 0.f, 0.f, 0.f};
  }

  #pragma unroll
  for (int kt = 0; kt < 8; ++kt) {
    short8v afr[8];
    #pragma unroll
    for (int mf = 0; mf < 8; ++mf) {
      int row = mf * 16 + lm;
      int c = (kt * 4 + lg) ^ (row & 7);
      afr[mf] = *(const short8v*)(&zl[row * 256 + c * 8]);
    }
    #pragma unroll
    for (int mf = 0; mf < 8; ++mf) {
      acc[mf][0] = __builtin_amdgcn_mfma_f32_16x16x32_bf16(afr[mf], bfr[0][kt], acc[mf][0], 0, 0, 0);
      acc[mf][1] = __builtin_amdgcn_mfma_f32_16x16x32_bf16(afr[mf], bfr[1][kt], acc[mf][1], 0, 0, 0);
    }
  }

  const float b0 = bl[nb + lm];
  const float b1 = bl[nb + 16 + lm];

  if (!SCORE) {
    #pragma unroll
    for (int mf = 0; mf < 8; ++mf) {
      #pragma unroll
      for (int r = 0; r < 4; ++r) {
        int row = node0 + mf * 16 + lg * 4 + r;
        if (row < NN) {
          hout[(size_t)row * DD + nb + lm]      = f2b(fmaxf(acc[mf][0][r] + b0, 0.f));
          hout[(size_t)row * DD + nb + 16 + lm] = f2b(fmaxf(acc[mf][1][r] + b1, 0.f));
        }
      }
    }
  } else {
    const float w0 = Ws[nb + lm];
    const float w1 = Ws[nb + 16 + lm];
    #pragma unroll
    for (int mf = 0; mf < 8; ++mf) {
      #pragma unroll
      for (int r = 0; r < 4; ++r) {
        float p = fmaxf(acc[mf][0][r] + b0, 0.f) * w0
                + fmaxf(acc[mf][1][r] + b1, 0.f) * w1;
        p += __shfl_xor(p, 1);
        p += __shfl_xor(p, 2);
        p += __shfl_xor(p, 4);
        p += __shfl_xor(p, 8);
        if (lm == 0) atomicAdd(&sbuf[mf * 16 + lg * 4 + r], p);
      }
    }
    __syncthreads();
    if (t < 128) {
      int node = node0 + t;
      if (node < NN) {
        float a = 1.f / (1.f + expf(-alphap[0]));
        float score = sbuf[t] + xw[node] + bsp[0];
        out[node] = a * rr[node] + (1.f - a) * score;
      }
    }
  }
}

// ---------------- launch ----------------

extern "C" void kernel_launch(void* const* d_in, const int* in_sizes, int n_in,
                              void* d_out, int out_size, void* d_ws, size_t ws_size,
                              hipStream_t stream) {
  const float* x   = (const float*)d_in[0];
  const int*   ei  = (const int*)d_in[1];
  const float* rr  = (const float*)d_in[2];
  const float* Wl1 = (const float*)d_in[3];
  const float* bl1 = (const float*)d_in[4];
  const float* Wr1 = (const float*)d_in[5];
  const float* Wl2 = (const float*)d_in[6];
  const float* bl2 = (const float*)d_in[7];
  const float* Wr2 = (const float*)d_in[8];
  const float* Wsc = (const float*)d_in[9];
  const float* bs  = (const float*)d_in[10];
  const float* al  = (const float*)d_in[11];
  const int* srcv = ei;
  const int* dstv = ei + NE;
  float* out = (float*)d_out;

  size_t off = 0;
  auto nxt = [&](size_t bytes) {
    size_t cur = off; off += (bytes + 255) & ~(size_t)255; return cur;
  };
  int*            ghist    = (int*)((char*)d_ws + nxt((size_t)B1 * NBUCK * 4));
  int*            goff     = (int*)((char*)d_ws + nxt((size_t)B1 * NBUCK * 4));
  int*            btot     = (int*)((char*)d_ws + nxt((size_t)NBUCK * 4));
  int*            binstart = (int*)((char*)d_ws + nxt((size_t)(NBUCK + 1) * 4));
  int*            rowptr   = (int*)((char*)d_ws + nxt((size_t)(NN + 1) * 4));
  int*            col      = (int*)((char*)d_ws + nxt((size_t)NE * 4));
  unsigned*       tmp      = (unsigned*)((char*)d_ws + nxt((size_t)NE * 4));
  unsigned short* xb       = (unsigned short*)((char*)d_ws + nxt((size_t)NN * DD * 2));
  unsigned short* aggb     = (unsigned short*)((char*)d_ws + nxt((size_t)NN * DD * 2));
  unsigned short* h1b      = (unsigned short*)((char*)d_ws + nxt((size_t)NN * DD * 2));
  unsigned short* W1       = (unsigned short*)((char*)d_ws + nxt((size_t)DD * 256 * 2));
  unsigned short* W2       = (unsigned short*)((char*)d_ws + nxt((size_t)DD * 256 * 2));
  float*          xw       = (float*)((char*)d_ws + nxt((size_t)NN * 4));

  hist1<<<B1, 256, 0, stream>>>(dstv, ghist);
  scan_cols<<<NBUCK, 256, 0, stream>>>(ghist, goff, btot);
  scan_btot<<<1, 256, 0, stream>>>(btot, binstart);
  scatter1<<<B1, 256, 0, stream>>>(srcv, dstv, goff, binstart, tmp);
  bucketsort<<<NBUCK, 256, 0, stream>>>(tmp, binstart, rowptr, col);

  conv_x<<<(NN + 3) / 4, 256, 0, stream>>>(x, Wsc, xb, xw);
  prep_w<<<256, 256, 0, stream>>>(Wl1, Wr1, Wl2, Wr2, W1, W2);

  // layer 1
  agg_csr<<<(NN * 16 + 255) / 256, 256, 0, stream>>>(xb, rowptr, col, aggb);
  linear_mfma<false><<<(NN + 127) / 128, 256, 0, stream>>>(
      aggb, xb, W1, bl1, h1b, nullptr, nullptr, nullptr, nullptr, nullptr, nullptr);
  // layer 2 (+ residual + score head + blend, fused)
  agg_csr<<<(NN * 16 + 255) / 256, 256, 0, stream>>>(h1b, rowptr, col, aggb);
  linear_mfma<true><<<(NN + 127) / 128, 256, 0, stream>>>(
      aggb, h1b, W2, bl2, nullptr, Wsc, bs, al, rr, xw, out);
}